// Round 1
// baseline (2267.245 us; speedup 1.0000x reference)
//
#include <hip/hip_runtime.h>

#define Bn 32
#define Ln 1024
#define En 512
#define On 512

// ---------------------------------------------------------------------------
// Generic fp32 tiled GEMM body: 64x64 output tile, BK=16, 256 threads, 4x4
// micro-tile per thread. TRANS_B: B operand is [N, K] row-major (used for
// Q*K^T). ADD_DELTA: fuse scores += sum_k delta_embedding[...,k] in epilogue.
// ---------------------------------------------------------------------------
template <bool TRANS_B, bool ADD_DELTA>
__device__ __forceinline__ void gemm_body(const float* __restrict__ A,
                                          const float* __restrict__ Bm,
                                          const float* __restrict__ delta4,
                                          float* __restrict__ C,
                                          int M, int N, int Kd) {
    __shared__ float As[16][65];
    __shared__ float Bs[16][65];
    const int tid = threadIdx.x;
    const int row0 = blockIdx.y * 64;
    const int col0 = blockIdx.x * 64;
    const int tx = tid & 15, ty = tid >> 4;
    const int ar = tid >> 2, ac = (tid & 3) * 4;     // A (and NT-B) load pattern
    const int bkr = tid >> 4, bcc = (tid & 15) * 4;  // NN-B load pattern

    float acc[4][4] = {};

    for (int k0 = 0; k0 < Kd; k0 += 16) {
        float4 av = *(const float4*)&A[(size_t)(row0 + ar) * Kd + k0 + ac];
        As[ac + 0][ar] = av.x;
        As[ac + 1][ar] = av.y;
        As[ac + 2][ar] = av.z;
        As[ac + 3][ar] = av.w;
        if (TRANS_B) {
            float4 bv = *(const float4*)&Bm[(size_t)(col0 + ar) * Kd + k0 + ac];
            Bs[ac + 0][ar] = bv.x;
            Bs[ac + 1][ar] = bv.y;
            Bs[ac + 2][ar] = bv.z;
            Bs[ac + 3][ar] = bv.w;
        } else {
            float4 bv = *(const float4*)&Bm[(size_t)(k0 + bkr) * N + col0 + bcc];
            *(float4*)&Bs[bkr][bcc] = bv;
        }
        __syncthreads();
#pragma unroll
        for (int kk = 0; kk < 16; ++kk) {
            float a[4], b[4];
#pragma unroll
            for (int x = 0; x < 4; ++x) {
                a[x] = As[kk][ty * 4 + x];
                b[x] = Bs[kk][tx * 4 + x];
            }
#pragma unroll
            for (int ii = 0; ii < 4; ++ii)
#pragma unroll
                for (int jj = 0; jj < 4; ++jj)
                    acc[ii][jj] = fmaf(a[ii], b[jj], acc[ii][jj]);
        }
        __syncthreads();
    }

#pragma unroll
    for (int ii = 0; ii < 4; ++ii) {
        const int i = row0 + ty * 4 + ii;
        float vals[4];
#pragma unroll
        for (int jj = 0; jj < 4; ++jj) {
            const int j = col0 + tx * 4 + jj;
            float r = acc[ii][jj];
            if (ADD_DELTA) {
                float4 dv = *(const float4*)&delta4[((size_t)i * N + j) * 4];
                r += (dv.x + dv.y) + (dv.z + dv.w);
            }
            vals[jj] = r;
        }
        float4 o = make_float4(vals[0], vals[1], vals[2], vals[3]);
        *(float4*)&C[(size_t)i * N + col0 + tx * 4] = o;
    }
}

// ---------------------------------------------------------------------------
// Pass 1: Q = X*Wq, K = X*Wk, V = X*Wv  (blockIdx.z selects which)
// ---------------------------------------------------------------------------
__global__ __launch_bounds__(256) void qkv_kernel(const float* __restrict__ X,
                                                  const float* __restrict__ Wq,
                                                  const float* __restrict__ Wk,
                                                  const float* __restrict__ Wv,
                                                  float* __restrict__ ws) {
    const int z = blockIdx.z;
    const float* W = (z == 0) ? Wq : (z == 1) ? Wk : Wv;
    float* Cptr = ws + (size_t)z * ((size_t)Bn * Ln * On);
    gemm_body<false, false>(X, W, nullptr, Cptr, Bn * Ln, On, En);
}

// ---------------------------------------------------------------------------
// Pass 2: S[b] = Q[b] * K[b]^T + sum_k delta[b,:,:,k]
// ---------------------------------------------------------------------------
__global__ __launch_bounds__(256) void scores_kernel(const float* __restrict__ Q,
                                                     const float* __restrict__ Kmat,
                                                     const float* __restrict__ delta,
                                                     float* __restrict__ S) {
    const int b = blockIdx.z;
    gemm_body<true, true>(Q + (size_t)b * Ln * On, Kmat + (size_t)b * Ln * On,
                          delta + (size_t)b * Ln * Ln * 4, S + (size_t)b * Ln * Ln,
                          Ln, Ln, On);
}

// ---------------------------------------------------------------------------
// Pass 3: per-row softmax over ALL 1024 keys, then post-softmax mask.
// One 256-thread block per (b, i) row; each thread owns 4 consecutive j.
// ---------------------------------------------------------------------------
__global__ __launch_bounds__(256) void softmax_kernel(float* __restrict__ S,
                                                      const int* __restrict__ traj) {
    const int row = blockIdx.x;  // b*L + i
    const int b = row >> 10;
    const int i = row & (Ln - 1);
    const int t = traj[b];
    float* Srow = S + (size_t)row * Ln;
    const int tid = threadIdx.x;
    const int j0 = tid * 4;

    if (i >= t) {  // whole output row masked -> P row = 0
        *(float4*)&Srow[j0] = make_float4(0.f, 0.f, 0.f, 0.f);
        return;
    }

    float4 v = *(const float4*)&Srow[j0];
    __shared__ float red[4];

    // block max (over all j, matching reference full softmax)
    float m = fmaxf(fmaxf(v.x, v.y), fmaxf(v.z, v.w));
#pragma unroll
    for (int off = 32; off >= 1; off >>= 1) m = fmaxf(m, __shfl_xor(m, off));
    if ((tid & 63) == 0) red[tid >> 6] = m;
    __syncthreads();
    m = fmaxf(fmaxf(red[0], red[1]), fmaxf(red[2], red[3]));
    __syncthreads();

    float e0 = expf(v.x - m), e1 = expf(v.y - m), e2 = expf(v.z - m), e3 = expf(v.w - m);
    float s = (e0 + e1) + (e2 + e3);
#pragma unroll
    for (int off = 32; off >= 1; off >>= 1) s += __shfl_xor(s, off);
    if ((tid & 63) == 0) red[tid >> 6] = s;
    __syncthreads();
    s = (red[0] + red[1]) + (red[2] + red[3]);
    const float inv = 1.0f / s;

    float4 o;
    o.x = (j0 + 0 < t) ? e0 * inv : 0.f;
    o.y = (j0 + 1 < t) ? e1 * inv : 0.f;
    o.z = (j0 + 2 < t) ? e2 * inv : 0.f;
    o.w = (j0 + 3 < t) ? e3 * inv : 0.f;
    *(float4*)&Srow[j0] = o;
}

// ---------------------------------------------------------------------------
// Pass 4: out[b] = P[b] * V[b]
// ---------------------------------------------------------------------------
__global__ __launch_bounds__(256) void pv_kernel(const float* __restrict__ P,
                                                 const float* __restrict__ V,
                                                 float* __restrict__ Out) {
    const int b = blockIdx.z;
    gemm_body<false, false>(P + (size_t)b * Ln * Ln, V + (size_t)b * Ln * On, nullptr,
                            Out + (size_t)b * Ln * On, Ln, On, Ln);
}

extern "C" void kernel_launch(void* const* d_in, const int* in_sizes, int n_in,
                              void* d_out, int out_size, void* d_ws, size_t ws_size,
                              hipStream_t stream) {
    const float* X = (const float*)d_in[0];      // [B, L, E]
    const float* delta = (const float*)d_in[1];  // [B, L, L, 4]
    const float* Wq = (const float*)d_in[2];     // [E, O]
    const float* Wk = (const float*)d_in[3];
    const float* Wv = (const float*)d_in[4];
    const int* traj = (const int*)d_in[5];       // [B]
    float* out = (float*)d_out;

    float* ws = (float*)d_ws;
    const size_t qkv_elems = (size_t)Bn * Ln * On;  // 16.77M each
    float* Q = ws;
    float* Km = ws + qkv_elems;
    float* V = ws + 2 * qkv_elems;
    float* S = ws + 3 * qkv_elems;  // [B, L, L] = 33.55M floats

    dim3 blk(256);
    qkv_kernel<<<dim3(On / 64, (Bn * Ln) / 64, 3), blk, 0, stream>>>(X, Wq, Wk, Wv, ws);
    scores_kernel<<<dim3(Ln / 64, Ln / 64, Bn), blk, 0, stream>>>(Q, Km, delta, S);
    softmax_kernel<<<dim3(Bn * Ln), blk, 0, stream>>>(S, traj);
    pv_kernel<<<dim3(On / 64, Ln / 64, Bn), blk, 0, stream>>>(S, V, out);
}

// Round 2
// 536.679 us; speedup vs baseline: 4.2246x; 4.2246x over previous
//
#include <hip/hip_runtime.h>
#include <hip/hip_bf16.h>

#define Bn 32
#define Ln 1024
#define En 512
#define On 512

typedef __attribute__((ext_vector_type(8))) short bf16x8;
typedef __attribute__((ext_vector_type(4))) float f32x4;

__device__ __forceinline__ ushort f2bf(float x) {
    __hip_bfloat16 h = __float2bfloat16(x);
    return *reinterpret_cast<ushort*>(&h);
}
__device__ __forceinline__ float bf2f(ushort u) {
    __hip_bfloat16 h;
    *reinterpret_cast<ushort*>(&h) = u;
    return __bfloat162float(h);
}

__device__ __forceinline__ f32x4 mfma_bf16(bf16x8 a, bf16x8 b, f32x4 c) {
    return __builtin_amdgcn_mfma_f32_16x16x32_bf16(a, b, c, 0, 0, 0);
}

// ---------------------------------------------------------------------------
// Transpose + split-convert W [E,O] fp32 -> Wt[n][k] hi/lo bf16, 3 matrices.
// ---------------------------------------------------------------------------
__global__ __launch_bounds__(256) void convert_w(const float* __restrict__ Wq,
                                                 const float* __restrict__ Wk,
                                                 const float* __restrict__ Wv,
                                                 ushort* __restrict__ wt) {
    const int z = blockIdx.z;
    const float* W = (z == 0) ? Wq : (z == 1) ? Wk : Wv;
    ushort* hi = wt + (size_t)z * 2 * (En * On);
    ushort* lo = hi + En * On;
    __shared__ float tile[32][33];
    const int n0 = blockIdx.x * 32, k0 = blockIdx.y * 32;
    const int tid = threadIdx.x;
    const int r = tid >> 3, c4 = (tid & 7) * 4;
    float4 wv = *(const float4*)&W[(size_t)(k0 + r) * On + n0 + c4];
    tile[r][c4 + 0] = wv.x;
    tile[r][c4 + 1] = wv.y;
    tile[r][c4 + 2] = wv.z;
    tile[r][c4 + 3] = wv.w;
    __syncthreads();
    ushort4 hs, ls;
    ushort* hp = &hs.x;
    ushort* lp = &ls.x;
#pragma unroll
    for (int jj = 0; jj < 4; ++jj) {
        float f = tile[c4 + jj][r];
        ushort h = f2bf(f);
        hp[jj] = h;
        lp[jj] = f2bf(f - bf2f(h));
    }
    *(ushort4*)&hi[(size_t)(n0 + r) * En + k0 + c4] = hs;
    *(ushort4*)&lo[(size_t)(n0 + r) * En + k0 + c4] = ls;
}

// ---------------------------------------------------------------------------
// Pass 1: Q/K (split hi/lo) and V (transposed bf16) via split-bf16 MFMA.
// 128x128 tile, BK=32, 256 threads = 4 waves (2x2), 16x16x32 MFMA.
// ---------------------------------------------------------------------------
__global__ __launch_bounds__(256) void gemm_qkv(const float* __restrict__ X,
                                                const ushort* __restrict__ wt,
                                                ushort* __restrict__ qhi, ushort* __restrict__ qlo,
                                                ushort* __restrict__ khi, ushort* __restrict__ klo,
                                                ushort* __restrict__ vt) {
    __shared__ short sAhi[128][40], sAlo[128][40], sBhi[128][40], sBlo[128][40];
    const int tid = threadIdx.x;
    const int z = blockIdx.z;
    const int row0 = blockIdx.y * 128;
    const int col0 = blockIdx.x * 128;
    const ushort* Whi = wt + (size_t)z * 2 * (En * On);
    const ushort* Wlo = Whi + En * On;

    const int lane = tid & 63, wave = tid >> 6;
    const int wr = (wave >> 1) * 64, wc = (wave & 1) * 64;
    const int ln = lane & 15, kb = (lane >> 4) * 8;

    f32x4 acc[4][4] = {};

    for (int k0 = 0; k0 < En; k0 += 32) {
#pragma unroll
        for (int cc = 0; cc < 2; ++cc) {
            const int c = tid + cc * 256;
            const int row = c >> 2, col = (c & 3) * 8;
            const float* xp = X + (size_t)(row0 + row) * En + k0 + col;
            float4 x0 = *(const float4*)xp;
            float4 x1 = *(const float4*)(xp + 4);
            float xs[8] = {x0.x, x0.y, x0.z, x0.w, x1.x, x1.y, x1.z, x1.w};
            bf16x8 hi, lo;
#pragma unroll
            for (int j = 0; j < 8; ++j) {
                ushort h = f2bf(xs[j]);
                hi[j] = (short)h;
                lo[j] = (short)f2bf(xs[j] - bf2f(h));
            }
            *(bf16x8*)&sAhi[row][col] = hi;
            *(bf16x8*)&sAlo[row][col] = lo;
            *(bf16x8*)&sBhi[row][col] = *(const bf16x8*)(Whi + (size_t)(col0 + row) * En + k0 + col);
            *(bf16x8*)&sBlo[row][col] = *(const bf16x8*)(Wlo + (size_t)(col0 + row) * En + k0 + col);
        }
        __syncthreads();
        bf16x8 bh[4], bl[4];
#pragma unroll
        for (int n = 0; n < 4; ++n) {
            bh[n] = *(bf16x8*)&sBhi[wc + n * 16 + ln][kb];
            bl[n] = *(bf16x8*)&sBlo[wc + n * 16 + ln][kb];
        }
#pragma unroll
        for (int m = 0; m < 4; ++m) {
            bf16x8 ah = *(bf16x8*)&sAhi[wr + m * 16 + ln][kb];
            bf16x8 al = *(bf16x8*)&sAlo[wr + m * 16 + ln][kb];
#pragma unroll
            for (int n = 0; n < 4; ++n) {
                acc[m][n] = mfma_bf16(ah, bh[n], acc[m][n]);
                acc[m][n] = mfma_bf16(ah, bl[n], acc[m][n]);
                acc[m][n] = mfma_bf16(al, bh[n], acc[m][n]);
            }
        }
        __syncthreads();
    }

    if (z < 2) {
        ushort* ho = (z == 0) ? qhi : khi;
        ushort* lo_o = (z == 0) ? qlo : klo;
#pragma unroll
        for (int m = 0; m < 4; ++m)
#pragma unroll
            for (int n = 0; n < 4; ++n)
#pragma unroll
                for (int r = 0; r < 4; ++r) {
                    const int gi = row0 + wr + m * 16 + (lane >> 4) * 4 + r;
                    const int gj = col0 + wc + n * 16 + ln;
                    const float v = acc[m][n][r];
                    const ushort h = f2bf(v);
                    const size_t idx = (size_t)gi * On + gj;
                    ho[idx] = h;
                    lo_o[idx] = f2bf(v - bf2f(h));
                }
    } else {
        const int b = row0 >> 10;
        const int lbase = row0 & (Ln - 1);
#pragma unroll
        for (int m = 0; m < 4; ++m)
#pragma unroll
            for (int n = 0; n < 4; ++n) {
                const int gj = col0 + wc + n * 16 + ln;                  // o
                const int l0 = lbase + wr + m * 16 + (lane >> 4) * 4;    // l
                ushort4 u;
                u.x = f2bf(acc[m][n][0]);
                u.y = f2bf(acc[m][n][1]);
                u.z = f2bf(acc[m][n][2]);
                u.w = f2bf(acc[m][n][3]);
                *(ushort4*)(vt + ((size_t)b * On + gj) * Ln + l0) = u;
            }
    }
}

// ---------------------------------------------------------------------------
// Pass 2: S[b] = Q[b]*K[b]^T (split-bf16 MFMA) + sum_k delta  -> fp32
// ---------------------------------------------------------------------------
__global__ __launch_bounds__(256) void gemm_scores(const ushort* __restrict__ qhi,
                                                   const ushort* __restrict__ qlo,
                                                   const ushort* __restrict__ khi,
                                                   const ushort* __restrict__ klo,
                                                   const float* __restrict__ delta,
                                                   float* __restrict__ S) {
    __shared__ short sAhi[128][40], sAlo[128][40], sBhi[128][40], sBlo[128][40];
    const int tid = threadIdx.x;
    const int b = blockIdx.z;
    const int row0 = blockIdx.y * 128;
    const int col0 = blockIdx.x * 128;

    const int lane = tid & 63, wave = tid >> 6;
    const int wr = (wave >> 1) * 64, wc = (wave & 1) * 64;
    const int ln = lane & 15, kb = (lane >> 4) * 8;

    f32x4 acc[4][4] = {};

    for (int k0 = 0; k0 < On; k0 += 32) {
#pragma unroll
        for (int cc = 0; cc < 2; ++cc) {
            const int c = tid + cc * 256;
            const int row = c >> 2, col = (c & 3) * 8;
            const size_t abase = ((size_t)b * Ln + row0 + row) * On + k0 + col;
            const size_t bbase = ((size_t)b * Ln + col0 + row) * On + k0 + col;
            *(bf16x8*)&sAhi[row][col] = *(const bf16x8*)(qhi + abase);
            *(bf16x8*)&sAlo[row][col] = *(const bf16x8*)(qlo + abase);
            *(bf16x8*)&sBhi[row][col] = *(const bf16x8*)(khi + bbase);
            *(bf16x8*)&sBlo[row][col] = *(const bf16x8*)(klo + bbase);
        }
        __syncthreads();
        bf16x8 bh[4], bl[4];
#pragma unroll
        for (int n = 0; n < 4; ++n) {
            bh[n] = *(bf16x8*)&sBhi[wc + n * 16 + ln][kb];
            bl[n] = *(bf16x8*)&sBlo[wc + n * 16 + ln][kb];
        }
#pragma unroll
        for (int m = 0; m < 4; ++m) {
            bf16x8 ah = *(bf16x8*)&sAhi[wr + m * 16 + ln][kb];
            bf16x8 al = *(bf16x8*)&sAlo[wr + m * 16 + ln][kb];
#pragma unroll
            for (int n = 0; n < 4; ++n) {
                acc[m][n] = mfma_bf16(ah, bh[n], acc[m][n]);
                acc[m][n] = mfma_bf16(ah, bl[n], acc[m][n]);
                acc[m][n] = mfma_bf16(al, bh[n], acc[m][n]);
            }
        }
        __syncthreads();
    }

#pragma unroll
    for (int m = 0; m < 4; ++m)
#pragma unroll
        for (int n = 0; n < 4; ++n)
#pragma unroll
            for (int r = 0; r < 4; ++r) {
                const int gi = row0 + wr + m * 16 + (lane >> 4) * 4 + r;
                const int gj = col0 + wc + n * 16 + ln;
                const float4 dv = *(const float4*)(delta + (((size_t)b * Ln + gi) * Ln + gj) * 4);
                S[((size_t)b * Ln + gi) * Ln + gj] = acc[m][n][r] + ((dv.x + dv.y) + (dv.z + dv.w));
            }
}

// ---------------------------------------------------------------------------
// Pass 3: full-row softmax (denominator over ALL j), post-softmax mask,
// write P as bf16 in-place into the S buffer (first 2048B of each 4KB row).
// ---------------------------------------------------------------------------
__global__ __launch_bounds__(256) void softmax_kernel(float* __restrict__ S,
                                                      const int* __restrict__ traj) {
    const int row = blockIdx.x;  // b*L + i
    const int b = row >> 10;
    const int i = row & (Ln - 1);
    const int t = traj[b];
    float* Srow = S + (size_t)row * Ln;
    ushort* Prow = (ushort*)Srow;
    const int tid = threadIdx.x;
    const int j0 = tid * 4;

    if (i >= t) {
        ushort4 z = {0, 0, 0, 0};
        *(ushort4*)&Prow[j0] = z;
        return;
    }

    float4 v = *(const float4*)&Srow[j0];
    __shared__ float red[4];

    float m = fmaxf(fmaxf(v.x, v.y), fmaxf(v.z, v.w));
#pragma unroll
    for (int off = 32; off >= 1; off >>= 1) m = fmaxf(m, __shfl_xor(m, off));
    if ((tid & 63) == 0) red[tid >> 6] = m;
    __syncthreads();
    m = fmaxf(fmaxf(red[0], red[1]), fmaxf(red[2], red[3]));
    __syncthreads();

    float e0 = expf(v.x - m), e1 = expf(v.y - m), e2 = expf(v.z - m), e3 = expf(v.w - m);
    float s = (e0 + e1) + (e2 + e3);
#pragma unroll
    for (int off = 32; off >= 1; off >>= 1) s += __shfl_xor(s, off);
    if ((tid & 63) == 0) red[tid >> 6] = s;
    __syncthreads();
    s = (red[0] + red[1]) + (red[2] + red[3]);
    const float inv = 1.0f / s;

    ushort4 o;
    o.x = (j0 + 0 < t) ? f2bf(e0 * inv) : (ushort)0;
    o.y = (j0 + 1 < t) ? f2bf(e1 * inv) : (ushort)0;
    o.z = (j0 + 2 < t) ? f2bf(e2 * inv) : (ushort)0;
    o.w = (j0 + 3 < t) ? f2bf(e3 * inv) : (ushort)0;
    *(ushort4*)&Prow[j0] = o;
}

// ---------------------------------------------------------------------------
// Pass 4: out[b] = P[b] (bf16, row stride 2048) * V[b]  (plain bf16 MFMA)
// ---------------------------------------------------------------------------
__global__ __launch_bounds__(256) void gemm_pv(const ushort* __restrict__ P,
                                               const ushort* __restrict__ vt,
                                               float* __restrict__ out) {
    __shared__ short sA[128][40], sB[128][40];
    const int tid = threadIdx.x;
    const int b = blockIdx.z;
    const int row0 = blockIdx.y * 128;
    const int col0 = blockIdx.x * 128;

    const int lane = tid & 63, wave = tid >> 6;
    const int wr = (wave >> 1) * 64, wc = (wave & 1) * 64;
    const int ln = lane & 15, kb = (lane >> 4) * 8;

    f32x4 acc[4][4] = {};

    for (int k0 = 0; k0 < Ln; k0 += 32) {
#pragma unroll
        for (int cc = 0; cc < 2; ++cc) {
            const int c = tid + cc * 256;
            const int row = c >> 2, col = (c & 3) * 8;
            *(bf16x8*)&sA[row][col] =
                *(const bf16x8*)(P + ((size_t)b * Ln + row0 + row) * 2048 + k0 + col);
            *(bf16x8*)&sB[row][col] =
                *(const bf16x8*)(vt + ((size_t)b * On + col0 + row) * Ln + k0 + col);
        }
        __syncthreads();
        bf16x8 bfr[4];
#pragma unroll
        for (int n = 0; n < 4; ++n) bfr[n] = *(bf16x8*)&sB[wc + n * 16 + ln][kb];
#pragma unroll
        for (int m = 0; m < 4; ++m) {
            bf16x8 a = *(bf16x8*)&sA[wr + m * 16 + ln][kb];
#pragma unroll
            for (int n = 0; n < 4; ++n) acc[m][n] = mfma_bf16(a, bfr[n], acc[m][n]);
        }
        __syncthreads();
    }

#pragma unroll
    for (int m = 0; m < 4; ++m)
#pragma unroll
        for (int n = 0; n < 4; ++n)
#pragma unroll
            for (int r = 0; r < 4; ++r) {
                const int gi = row0 + wr + m * 16 + (lane >> 4) * 4 + r;
                const int gj = col0 + wc + n * 16 + ln;
                out[((size_t)b * Ln + gi) * On + gj] = acc[m][n][r];
            }
}

extern "C" void kernel_launch(void* const* d_in, const int* in_sizes, int n_in,
                              void* d_out, int out_size, void* d_ws, size_t ws_size,
                              hipStream_t stream) {
    const float* X = (const float*)d_in[0];      // [B, L, E]
    const float* delta = (const float*)d_in[1];  // [B, L, L, 4]
    const float* Wq = (const float*)d_in[2];     // [E, O]
    const float* Wk = (const float*)d_in[3];
    const float* Wv = (const float*)d_in[4];
    const int* traj = (const int*)d_in[5];       // [B]
    float* out = (float*)d_out;

    // ws layout (ushort units unless noted)
    ushort* wt = (ushort*)d_ws;                       // 3*2*256K = 1.5M shorts
    ushort* qhi = wt + 3 * 2 * (size_t)(En * On);
    ushort* qlo = qhi + (size_t)Bn * Ln * On;
    ushort* khi = qlo + (size_t)Bn * Ln * On;
    ushort* klo = khi + (size_t)Bn * Ln * On;
    ushort* vt = klo + (size_t)Bn * Ln * On;          // [B][O][L]
    float* S = (float*)(vt + (size_t)Bn * Ln * On);   // [B][L][L] fp32 / P bf16 in place

    convert_w<<<dim3(On / 32, En / 32, 3), 256, 0, stream>>>(Wq, Wk, Wv, wt);
    gemm_qkv<<<dim3(On / 128, (Bn * Ln) / 128, 3), 256, 0, stream>>>(X, wt, qhi, qlo, khi, klo, vt);
    gemm_scores<<<dim3(Ln / 128, Ln / 128, Bn), 256, 0, stream>>>(qhi, qlo, khi, klo, delta, S);
    softmax_kernel<<<dim3(Bn * Ln), 256, 0, stream>>>(S, traj);
    gemm_pv<<<dim3(On / 128, Ln / 128, Bn), 256, 0, stream>>>((const ushort*)S, vt, out);
}